// Round 6
// baseline (537.795 us; speedup 1.0000x reference)
//
#include <hip/hip_runtime.h>
#include <hip/hip_cooperative_groups.h>

namespace cg = cooperative_groups;

typedef __bf16 bf16_t;
typedef __bf16 bf16x4 __attribute__((ext_vector_type(4)));
typedef __bf16 bf16x8 __attribute__((ext_vector_type(8)));
typedef float floatx4 __attribute__((ext_vector_type(4)));

#define G_GRAPHS 64
#define N_NODES 2000
#define N_EDGES 64000
#define BATCH 10000
#define TED_ 512
#define NOISE_ 128
#define PACDIM_ 6400
#define D0_ 1024
#define D1_ 512
#define MROWS 1000   // BATCH / PAC
#define ESPLIT 8
#define EPB (N_EDGES / ESPLIT)      // 8000 edges per split block
#define S0 8          // split-K for layer 0

// prep block ranges (pack | W0 transpose | W1 transpose)
#define PACK_BLKS 1250   // 4 float4 per thread
#define W0T_BLKS 1600    // (6400/64)*(1024/64)
#define W1T_BLKS 128     // (1024/64)*(512/64)

// ---------------- async global->LDS helper (16B per lane) ----------------
__device__ __forceinline__ void glds16(const void* g, void* l) {
    __builtin_amdgcn_global_load_lds(
        (__attribute__((address_space(1))) void*)(g),
        (__attribute__((address_space(3))) void*)(l), 16, 0, 0);
}

// ========== kernel G: cooperative fused deg + msg + gnoise ==========
// 512 blocks x 512 threads (2 blocks/CU co-resident).
// phase 1: degree histogram partials  -> degs_part[g][s][2000]
// phase 2: message-pass partials      -> outs_part[g][s][2000]
// phase 3 (blocks<256): finish GCN + gnoise partial GEMV -> gnoise_p
__global__ __launch_bounds__(512) void graph_kernel(
    const float* __restrict__ graphs_x, const int* __restrict__ edge_index,
    float* __restrict__ degs_part, float* __restrict__ outs_part,
    const float* __restrict__ gcn_w, const float* __restrict__ gcn_b,
    const float* __restrict__ gme_w, float* __restrict__ gnoise_p)
{
    __shared__ __align__(16) float sm[3 * N_NODES];   // 24 KB
    cg::grid_group grid = cg::this_grid();
    const int b = blockIdx.x, tid = threadIdx.x;
    const int s = b & 7, g = b >> 3;

    // ---- phase 1: degree histogram (LDS atomics, plain global writes) ----
    {
        float* h = sm;
        for (int n = tid; n < N_NODES; n += 512) h[n] = 0.f;
        __syncthreads();
        const int4* d4 = (const int4*)(edge_index + (size_t)g * 2 * N_EDGES
                                       + N_EDGES + s * EPB);
        for (int e = tid; e < EPB / 4; e += 512) {
            int4 v = d4[e];
            atomicAdd(&h[v.x], 1.0f); atomicAdd(&h[v.y], 1.0f);
            atomicAdd(&h[v.z], 1.0f); atomicAdd(&h[v.w], 1.0f);
        }
        __syncthreads();
        float* dp = degs_part + ((size_t)g * ESPLIT + s) * N_NODES;
        for (int n = tid; n < N_NODES; n += 512) dp[n] = h[n];
    }
    __threadfence();
    grid.sync();

    // ---- phase 2: message pass partials ----
    {
        float* ys  = sm;                 // x[n]*dinv[n]
        float* dvl = sm + N_NODES;       // dinv[n]
        float* oh  = sm + 2 * N_NODES;
        const float* xg = graphs_x + (size_t)g * N_NODES;
        const float* dgp = degs_part + (size_t)g * ESPLIT * N_NODES;
        for (int n = tid; n < N_NODES; n += 512) {
            float d = 1.0f;                            // +1 self-loop
            for (int p = 0; p < ESPLIT; p++) d += dgp[(size_t)p * N_NODES + n];
            float dv = rsqrtf(d);
            dvl[n] = dv;
            ys[n] = xg[n] * dv;
            oh[n] = 0.f;
        }
        __syncthreads();
        const int* src = edge_index + (size_t)g * 2 * N_EDGES + s * EPB;
        const int2* s2 = (const int2*)src;
        const int2* d2 = (const int2*)(src + N_EDGES);
        for (int e = tid; e < EPB / 2; e += 512) {
            int2 sv = s2[e], dd = d2[e];
            atomicAdd(&oh[dd.x], ys[sv.x] * dvl[dd.x]);
            atomicAdd(&oh[dd.y], ys[sv.y] * dvl[dd.y]);
        }
        __syncthreads();
        float* op = outs_part + ((size_t)g * ESPLIT + s) * N_NODES;
        for (int n = tid; n < N_NODES; n += 512) op[n] = oh[n];
    }
    __threadfence();
    grid.sync();

    // ---- phase 3: finish GCN + gnoise partial GEMV (blocks 0..255) ----
    if (b < 256) {
        const int s3 = b & 3, g3 = b >> 2;
        float* of = sm;                               // [500]
        float (*part)[128] = (float(*)[128])(sm + 512);
        const int nBase = s3 * 500;
        const float w = gcn_w[0], bb = gcn_b[0];
        const float* dgp = degs_part + (size_t)g3 * ESPLIT * N_NODES;
        const float* otp = outs_part + (size_t)g3 * ESPLIT * N_NODES;
        for (int n = tid; n < 500; n += 512) {
            int gn = nBase + n;
            float d = 1.0f, o = 0.f;
            for (int p = 0; p < ESPLIT; p++) {
                d += dgp[(size_t)p * N_NODES + gn];
                o += otp[(size_t)p * N_NODES + gn];
            }
            of[n] = w * (o + graphs_x[(size_t)g3 * N_NODES + gn] / d) + bb;
        }
        __syncthreads();
        const int j = tid & 127, ch = tid >> 7;
        float acc = 0.f;
        const int n0 = ch * 125;
        for (int n = n0; n < n0 + 125; n++)
            acc += of[n] * gme_w[(size_t)(nBase + n) * 128 + j];
        part[ch][j] = acc;
        __syncthreads();
        if (tid < 128)
            gnoise_p[((size_t)g3 * 4 + s3) * 128 + tid] =
                part[0][tid] + part[1][tid] + part[2][tid] + part[3][tid];
    }
}

// ------------- kernel A: prep (pack input | transpose W0/W1, vectorized) -------------
__global__ __launch_bounds__(256) void prep_kernel(
    const float* __restrict__ in, bf16_t* __restrict__ A,
    const float* __restrict__ W0, bf16_t* __restrict__ W0t,
    const float* __restrict__ W1, bf16_t* __restrict__ W1t)
{
    __shared__ float t[64][67];   // 17.2 KB, bank-safe for both phases
    const int b = blockIdx.x, tid = threadIdx.x;
    if (b < PACK_BLKS) {
        int base = b * 1024;                        // 4 float4 per thread
        for (int u = 0; u < 4; u++) {
            int idx = base + u * 256 + tid;         // over BATCH*512/4
            float4 v = ((const float4*)in)[idx];
            int bb = idx >> 7;
            int c = (idx & 127) << 2;
            int r = bb / 10, slot = bb - r * 10;
            bf16x4 o = { (bf16_t)v.x, (bf16_t)v.y, (bf16_t)v.z, (bf16_t)v.w };
            *(bf16x4*)(A + (size_t)r * PACDIM_ + slot * 640 + c) = o;
        }
        return;
    }
    // transpose-convert: W [Rr rows][Cc cols] fp32 -> Wt [Cc][Rr] bf16, 64x64 tiles
    const float* W; bf16_t* Wt; int Rr, Cc, r0, c0;
    if (b < PACK_BLKS + W0T_BLKS) {
        int tile = b - PACK_BLKS;                   // 100 x 16 tiles
        W = W0; Wt = W0t; Rr = PACDIM_; Cc = D0_;
        r0 = (tile >> 4) << 6; c0 = (tile & 15) << 6;
    } else {
        int tile = b - (PACK_BLKS + W0T_BLKS);      // 16 x 8 tiles
        W = W1; Wt = W1t; Rr = D0_; Cc = D1_;
        r0 = (tile >> 3) << 6; c0 = (tile & 7) << 6;
    }
    for (int u = 0; u < 4; u++) {
        int idx = u * 256 + tid;
        int r = idx >> 4, c4 = (idx & 15) << 2;
        float4 v = *(const float4*)(W + (size_t)(r0 + r) * Cc + c0 + c4);
        t[r][c4] = v.x; t[r][c4 + 1] = v.y; t[r][c4 + 2] = v.z; t[r][c4 + 3] = v.w;
    }
    __syncthreads();
    for (int u = 0; u < 2; u++) {
        int widx = u * 256 + tid;
        int c = widx >> 3, seg = widx & 7;
        bf16x8 o;
        for (int jj = 0; jj < 8; jj++) o[jj] = (bf16_t)t[seg * 8 + jj][c];
        *(bf16x8*)(Wt + (size_t)(c0 + c) * Rr + r0 + seg * 8) = o;
    }
}

// ------- kernel D: meta MLP + noise cols -> A (sums 4 gnoise partials inline) -------
__global__ __launch_bounds__(256) void meta_kernel(
    const float* __restrict__ chain, const float* __restrict__ metadata,
    const int* __restrict__ graph_ids,
    const float* __restrict__ meta_w, const float* __restrict__ meta_b,
    const float* __restrict__ gme_w, const float* __restrict__ gme_b,
    const float* __restrict__ gnoise_p, bf16_t* __restrict__ A)
{
    int wid = (blockIdx.x * 256 + threadIdx.x) >> 6;
    int lane = threadIdx.x & 63;
    if (wid >= BATCH) return;
    const int b = wid;
    float me = 0.f;
    if (lane < 32) {
        me = meta_b[lane] + chain[b] * meta_w[lane];
        for (int i = 1; i < 16; i++)
            me += metadata[(size_t)b * 15 + (i - 1)] * meta_w[(size_t)i * 32 + lane];
        me = me > 0.f ? me : 0.f;
    }
    const int gid = graph_ids[b];
    const float* gp = gnoise_p + (size_t)gid * 4 * 128;
    const int j1 = lane, j2 = lane + 64;
    float n1 = gme_b[j1] + gp[j1] + gp[128 + j1] + gp[256 + j1] + gp[384 + j1];
    float n2 = gme_b[j2] + gp[j2] + gp[128 + j2] + gp[256 + j2] + gp[384 + j2];
    for (int k = 0; k < 32; k++) {
        float mk = __shfl(me, k, 64);
        const float* wrow = gme_w + (size_t)(N_NODES + k) * 128;
        n1 += mk * wrow[j1];
        n2 += mk * wrow[j2];
    }
    int r = b / 10, slot = b - r * 10;
    bf16_t* dp = A + (size_t)r * PACDIM_ + slot * 640 + TED_;
    dp[j1] = (bf16_t)n1;
    dp[j2] = (bf16_t)n2;
}

// -------- kernel 5: split-K GEMM (layer 0), double-buffered, XOR-swizzled LDS --------
__global__ __launch_bounds__(256) void gemm_bt_splitk_kernel(
    const bf16_t* __restrict__ A,   // [M,K] row-major
    const bf16_t* __restrict__ Bt,  // [N,K] row-major
    float* __restrict__ P,          // [S, Mp, N] fp32 partials
    int M, int N, int K, int KS, int zbits, int xbits, int Mp)
{
    __shared__ __align__(16) bf16_t As[2][128 * 32];
    __shared__ __align__(16) bf16_t Bs[2][128 * 32];
    const int tid = threadIdx.x;
    const int wave = tid >> 6;
    const int lane = tid & 63;
    const int id = blockIdx.x;
    const int z = id & ((1 << zbits) - 1);
    const int xt = (id >> zbits) & ((1 << xbits) - 1);
    const int yt = id >> (zbits + xbits);
    const int mBase = yt * 128;
    const int nBase = xt * 128;
    const int wm = (wave & 1) * 64;
    const int wn = (wave >> 1) * 64;

    floatx4 acc[4][4] = {};

    const int rA0 = tid >> 2;
    const int g4 = tid & 3;
    const int f4 = (rA0 >> 1) & 3;
    const int k8 = (g4 ^ f4) * 8;
    int gm0 = mBase + rA0;      if (gm0 > M - 1) gm0 = M - 1;
    int gm1 = mBase + 64 + rA0; if (gm1 > M - 1) gm1 = M - 1;
    const bf16_t* aP0 = A + (size_t)gm0 * K + k8;
    const bf16_t* aP1 = A + (size_t)gm1 * K + k8;
    const bf16_t* bP0 = Bt + (size_t)(nBase + rA0) * K + k8;
    const bf16_t* bP1 = Bt + (size_t)(nBase + 64 + rA0) * K + k8;

    const int q4 = lane >> 4;
    const int mr = lane & 15;
    const int kq = ((q4 ^ ((mr >> 1) & 3)) * 8);
    int aOff[4], bOff[4];
    for (int i = 0; i < 4; i++) aOff[i] = (wm + i * 16 + mr) * 32 + kq;
    for (int j = 0; j < 4; j++) bOff[j] = (wn + j * 16 + mr) * 32 + kq;

    const int nIter = KS >> 5;
    const int kc = z * KS;
    {   // prologue: stage tile 0 into buffer 0
        char* lA = (char*)(&As[0][0]) + wave * 1024;
        char* lB = (char*)(&Bs[0][0]) + wave * 1024;
        glds16(aP0 + kc, lA);
        glds16(aP1 + kc, lA + 4096);
        glds16(bP0 + kc, lB);
        glds16(bP1 + kc, lB + 4096);
    }
    __syncthreads();
    for (int t = 0; t < nIter; ++t) {
        const int cur = t & 1;
        if (t + 1 < nIter) {
            const int kn = kc + (t + 1) * 32;
            char* lA = (char*)(&As[cur ^ 1][0]) + wave * 1024;
            char* lB = (char*)(&Bs[cur ^ 1][0]) + wave * 1024;
            glds16(aP0 + kn, lA);
            glds16(aP1 + kn, lA + 4096);
            glds16(bP0 + kn, lB);
            glds16(bP1 + kn, lB + 4096);
        }
        const bf16_t* aB = &As[cur][0];
        const bf16_t* bB = &Bs[cur][0];
        bf16x8 af[4], bfr[4];
        for (int i = 0; i < 4; i++) af[i] = *(const bf16x8*)(aB + aOff[i]);
        for (int j = 0; j < 4; j++) bfr[j] = *(const bf16x8*)(bB + bOff[j]);
        for (int i = 0; i < 4; i++)
            for (int j = 0; j < 4; j++)
                acc[i][j] = __builtin_amdgcn_mfma_f32_16x16x32_bf16(
                    af[i], bfr[j], acc[i][j], 0, 0, 0);
        __syncthreads();
    }

    float* Pz = P + (size_t)z * Mp * N;
    const int rq = (lane >> 4) * 4;
    const int cn = lane & 15;
    for (int j = 0; j < 4; j++) {
        int col = nBase + wn + j * 16 + cn;
        for (int i = 0; i < 4; i++)
            for (int r = 0; r < 4; r++) {
                int rowm = mBase + wm + i * 16 + rq + r;
                Pz[(size_t)rowm * N + col] = acc[i][j][r];
            }
    }
}

// -------- kernel 5b: reduce split-K partials + bias + leaky -> bf16; seed out=b2 --------
__global__ __launch_bounds__(256) void reduce_bias_leaky_kernel(
    const float* __restrict__ P, const float* __restrict__ bias,
    bf16_t* __restrict__ C, int M, int N, int Mp, int S,
    const float* __restrict__ b2, float* __restrict__ outp)
{
    if (blockIdx.x == 0 && threadIdx.x < MROWS / 4) {
        float bb2 = b2[0];
        ((float4*)outp)[threadIdx.x] = make_float4(bb2, bb2, bb2, bb2);
    }
    int idx = blockIdx.x * 256 + threadIdx.x;
    int total = M * (N >> 2);
    if (idx >= total) return;
    int nv = N >> 2;
    int r = idx / nv, c4 = (idx - r * nv) << 2;
    size_t off = (size_t)r * N + c4;
    size_t stride = (size_t)Mp * N;
    float4 v = *(const float4*)(P + off);
    for (int s = 1; s < S; s++) {
        float4 u = *(const float4*)(P + s * stride + off);
        v.x += u.x; v.y += u.y; v.z += u.z; v.w += u.w;
    }
    const float4 bv = *(const float4*)(bias + c4);
    v.x += bv.x; v.y += bv.y; v.z += bv.z; v.w += bv.w;
    v.x = v.x > 0.f ? v.x : 0.2f * v.x;
    v.y = v.y > 0.f ? v.y : 0.2f * v.y;
    v.z = v.z > 0.f ? v.z : 0.2f * v.z;
    v.w = v.w > 0.f ? v.w : 0.2f * v.w;
    bf16x4 o = { (bf16_t)v.x, (bf16_t)v.y, (bf16_t)v.z, (bf16_t)v.w };
    *(bf16x4*)(C + off) = o;
}

// ---- kernel 6: gemm1 (non-split, K=1024) + fused bias/leaky/dot(w2) -> atomicAdd out ----
// BM=BN=128, grid 32 blocks (x=4, y=8)
__global__ __launch_bounds__(256) void gemm1_final_kernel(
    const bf16_t* __restrict__ A,   // H1 [MROWS,1024] row-major (bf16)
    const bf16_t* __restrict__ Bt,  // W1t [512,1024] row-major (bf16)
    const float* __restrict__ b1, const float* __restrict__ w2,
    float* __restrict__ outp)
{
    __shared__ __align__(16) bf16_t As[2][128 * 32];
    __shared__ __align__(16) bf16_t Bs[2][128 * 32];
    const int K = D0_;
    const int tid = threadIdx.x;
    const int wave = tid >> 6;
    const int lane = tid & 63;
    const int xt = blockIdx.x & 3;
    const int yt = blockIdx.x >> 2;
    const int mBase = yt * 128;
    const int nBase = xt * 128;
    const int wm = (wave & 1) * 64;
    const int wn = (wave >> 1) * 64;

    floatx4 acc[4][4] = {};

    const int rA0 = tid >> 2;
    const int g4 = tid & 3;
    const int f4 = (rA0 >> 1) & 3;
    const int k8 = (g4 ^ f4) * 8;
    int gm0 = mBase + rA0;      if (gm0 > MROWS - 1) gm0 = MROWS - 1;
    int gm1 = mBase + 64 + rA0; if (gm1 > MROWS - 1) gm1 = MROWS - 1;
    const bf16_t* aP0 = A + (size_t)gm0 * K + k8;
    const bf16_t* aP1 = A + (size_t)gm1 * K + k8;
    const bf16_t* bP0 = Bt + (size_t)(nBase + rA0) * K + k8;
    const bf16_t* bP1 = Bt + (size_t)(nBase + 64 + rA0) * K + k8;

    const int q4 = lane >> 4;
    const int mr = lane & 15;
    const int kq = ((q4 ^ ((mr >> 1) & 3)) * 8);
    int aOff[4], bOff[4];
    for (int i = 0; i < 4; i++) aOff[i] = (wm + i * 16 + mr) * 32 + kq;
    for (int j = 0; j < 4; j++) bOff[j] = (wn + j * 16 + mr) * 32 + kq;

    const int nIter = K >> 5;   // 32
    {
        char* lA = (char*)(&As[0][0]) + wave * 1024;
        char* lB = (char*)(&Bs[0][0]) + wave * 1024;
        glds16(aP0, lA);
        glds16(aP1, lA + 4096);
        glds16(bP0, lB);
        glds16(bP1, lB + 4096);
    }
    __syncthreads();
    for (int t = 0; t < nIter; ++t) {
        const int cur = t & 1;
        if (t + 1 < nIter) {
            const int kn = (t + 1) * 32;
            char* lA = (char*)(&As[cur ^ 1][0]) + wave * 1024;
            char* lB = (char*)(&Bs[cur ^ 1][0]) + wave * 1024;
            glds16(aP0 + kn, lA);
            glds16(aP1 + kn, lA + 4096);
            glds16(bP0 + kn, lB);
            glds16(bP1 + kn, lB + 4096);
        }
        const bf16_t* aB = &As[cur][0];
        const bf16_t* bB = &Bs[cur][0];
        bf16x8 af[4], bfr[4];
        for (int i = 0; i < 4; i++) af[i] = *(const bf16x8*)(aB + aOff[i]);
        for (int j = 0; j < 4; j++) bfr[j] = *(const bf16x8*)(bB + bOff[j]);
        for (int i = 0; i < 4; i++)
            for (int j = 0; j < 4; j++)
                acc[i][j] = __builtin_amdgcn_mfma_f32_16x16x32_bf16(
                    af[i], bfr[j], acc[i][j], 0, 0, 0);
        __syncthreads();
    }

    // epilogue: out[row] += sum_j leaky(acc + b1[col]) * w2[col]
    const int cn = lane & 15;
    float b1v[4], w2v[4];
    for (int j = 0; j < 4; j++) {
        int col = nBase + wn + j * 16 + cn;
        b1v[j] = b1[col];
        w2v[j] = w2[col];
    }
    for (int i = 0; i < 4; i++) {
        for (int r = 0; r < 4; r++) {
            float part = 0.f;
            for (int j = 0; j < 4; j++) {
                float v = acc[i][j][r] + b1v[j];
                v = v > 0.f ? v : 0.2f * v;
                part += v * w2v[j];
            }
            for (int off = 8; off; off >>= 1) part += __shfl_xor(part, off, 16);
            if (cn == 0) {
                int rowm = mBase + wm + i * 16 + q4 * 4 + r;
                if (rowm < MROWS) atomicAdd(&outp[rowm], part);
            }
        }
    }
}

// ---------------------------- launcher ----------------------------
extern "C" void kernel_launch(void* const* d_in, const int* in_sizes, int n_in,
                              void* d_out, int out_size, void* d_ws, size_t ws_size,
                              hipStream_t stream)
{
    const float* input_    = (const float*)d_in[0];
    const float* graphs_x  = (const float*)d_in[1];
    const int*   edge_idx  = (const int*)  d_in[2];
    const int*   graph_ids = (const int*)  d_in[3];
    const float* chain     = (const float*)d_in[4];
    const float* metadata  = (const float*)d_in[5];
    const float* gcn_w     = (const float*)d_in[6];
    const float* gcn_b     = (const float*)d_in[7];
    const float* meta_w    = (const float*)d_in[8];
    const float* meta_b    = (const float*)d_in[9];
    const float* gme_w     = (const float*)d_in[10];
    const float* gme_b     = (const float*)d_in[11];
    const float* seq_w0    = (const float*)d_in[12];
    const float* seq_b0    = (const float*)d_in[13];
    const float* seq_w1    = (const float*)d_in[14];
    const float* seq_b1    = (const float*)d_in[15];
    const float* seq_w2    = (const float*)d_in[16];
    const float* seq_b2    = (const float*)d_in[17];
    float* out = (float*)d_out;

    char* ws = (char*)d_ws;
    // workspace layout (no pre-zeroing needed anywhere: all plain writes)
    float*  degs_part = (float*)(ws + 0);            // 64*8*2000*4  =  4,096,000
    float*  outs_part = (float*)(ws + 4096000);      // 64*8*2000*4  =  4,096,000
    float*  gnoise_p  = (float*)(ws + 8192000);      // 64*4*128*4   =    131,072
    bf16_t* Abuf      = (bf16_t*)(ws + 8323072);     // 1000*6400*2  = 12,800,000
    bf16_t* W0t       = (bf16_t*)(ws + 21123072);    // 6400*1024*2  = 13,107,200
    bf16_t* W1t       = (bf16_t*)(ws + 34230272);    // 1024*512*2   =  1,048,576
    bf16_t* H1        = (bf16_t*)(ws + 35278848);    // 1000*1024*2  =  2,048,000
    float*  P         = (float*)(ws + 37326848);     // 8*1024*1024*4 = 33,554,432
    // total ~70.9 MB

    // G: cooperative fused deg + msg + gnoise (2 blocks/CU co-resident)
    void* gargs[] = {
        (void*)&graphs_x, (void*)&edge_idx, (void*)&degs_part, (void*)&outs_part,
        (void*)&gcn_w, (void*)&gcn_b, (void*)&gme_w, (void*)&gnoise_p
    };
    hipLaunchCooperativeKernel(graph_kernel, dim3(512), dim3(512), gargs, 0, stream);

    // A: pack input | transpose W0 | transpose W1 (vectorized, streaming)
    prep_kernel<<<PACK_BLKS + W0T_BLKS + W1T_BLKS, 256, 0, stream>>>(
        input_, Abuf, seq_w0, W0t, seq_w1, W1t);

    // D: meta MLP + noise columns into A
    meta_kernel<<<2500, 256, 0, stream>>>(
        chain, metadata, graph_ids, meta_w, meta_b, gme_w, gme_b,
        gnoise_p, Abuf);

    // layer 0: M=1000 N=1024 K=6400, split-K=8 (KS=800), 8x8x8=512 blocks flat
    gemm_bt_splitk_kernel<<<512, 256, 0, stream>>>(
        Abuf, W0t, P, MROWS, D0_, PACDIM_, PACDIM_ / S0, 3, 3, 1024);
    // reduce P -> H1 (bias+leaky, bf16); also seeds out[r] = b2
    reduce_bias_leaky_kernel<<<(MROWS * D0_ / 4 + 255) / 256, 256, 0, stream>>>(
        P, seq_b0, H1, MROWS, D0_, 1024, S0, seq_b2, out);

    // layer 1 fused with final: M=1000 N=512 K=1024, 4x8=32 blocks
    gemm1_final_kernel<<<32, 256, 0, stream>>>(
        H1, W1t, seq_b1, seq_w2, out);
}

// Round 7
// 255.655 us; speedup vs baseline: 2.1036x; 2.1036x over previous
//
#include <hip/hip_runtime.h>

typedef __bf16 bf16_t;
typedef __bf16 bf16x4 __attribute__((ext_vector_type(4)));
typedef __bf16 bf16x8 __attribute__((ext_vector_type(8)));
typedef float floatx4 __attribute__((ext_vector_type(4)));

#define G_GRAPHS 64
#define N_NODES 2000
#define N_EDGES 64000
#define BATCH 10000
#define TED_ 512
#define NOISE_ 128
#define PACDIM_ 6400
#define D0_ 1024
#define D1_ 512
#define MROWS 1000   // BATCH / PAC
#define ESPLIT 8
#define EPB (N_EDGES / ESPLIT)      // 8000 edges per split block
#define MSPLIT 8
#define S0 8          // split-K for layer 0

// work kernel block ranges: msg | pack | W0 transpose | W1 transpose
#define MSG_BLKS 512
#define PACK_BLKS 625    // 2048 float4 per block (4 per thread, 512 thr)
#define W0T_BLKS 1600    // (6400/64)*(1024/64)
#define W1T_BLKS 128     // (1024/64)*(512/64)

// ---------------- async global->LDS helper (16B per lane) ----------------
__device__ __forceinline__ void glds16(const void* g, void* l) {
    __builtin_amdgcn_global_load_lds(
        (__attribute__((address_space(1))) void*)(g),
        (__attribute__((address_space(3))) void*)(l), 16, 0, 0);
}

// ---------- kernel 1: degree histogram partials (no global atomics) ----------
__global__ __launch_bounds__(512) void deg_kernel(
    const int* __restrict__ edge_index, float* __restrict__ degs_part)
{
    __shared__ float h[N_NODES];
    const int b = blockIdx.x, tid = threadIdx.x;
    const int s = b & 7, g = b >> 3;
    for (int n = tid; n < N_NODES; n += 512) h[n] = 0.f;
    __syncthreads();
    const int4* d4 = (const int4*)(edge_index + (size_t)g * 2 * N_EDGES
                                   + N_EDGES + s * EPB);
    for (int e = tid; e < EPB / 4; e += 512) {
        int4 v = d4[e];
        atomicAdd(&h[v.x], 1.0f); atomicAdd(&h[v.y], 1.0f);
        atomicAdd(&h[v.z], 1.0f); atomicAdd(&h[v.w], 1.0f);
    }
    __syncthreads();
    float* dp = degs_part + ((size_t)g * ESPLIT + s) * N_NODES;
    for (int n = tid; n < N_NODES; n += 512) dp[n] = h[n];
}

// ========== kernel 2: work (msg | pack input | transpose W0/W1) ==========
// blocks [0,512): message-pass partials (latency-bound, LDS atomics)
// blocks [512,1137): pack input_ -> A bf16 (streaming, hides under msg)
// blocks [1137,2737): transpose W0 -> W0t bf16 (vectorized)
// blocks [2737,2865): transpose W1 -> W1t bf16 (vectorized)
__global__ __launch_bounds__(512) void work_kernel(
    const float* __restrict__ graphs_x, const int* __restrict__ edge_index,
    const float* __restrict__ degs_part, float* __restrict__ outs_part,
    const float* __restrict__ in, bf16_t* __restrict__ A,
    const float* __restrict__ W0, bf16_t* __restrict__ W0t,
    const float* __restrict__ W1, bf16_t* __restrict__ W1t)
{
    __shared__ __align__(16) float sm[3 * N_NODES];   // 24 KB; aliased by transpose
    const int b = blockIdx.x, tid = threadIdx.x;

    if (b < MSG_BLKS) {
        float* ys  = sm;                 // x[n]*dinv[n]
        float* dvl = sm + N_NODES;       // dinv[n]
        float* oh  = sm + 2 * N_NODES;
        const int s = b & 7, g = b >> 3;
        const float* xg = graphs_x + (size_t)g * N_NODES;
        const float* dgp = degs_part + (size_t)g * ESPLIT * N_NODES;
        for (int n = tid; n < N_NODES; n += 512) {
            float d = 1.0f;                            // +1 self-loop
            for (int p = 0; p < ESPLIT; p++) d += dgp[(size_t)p * N_NODES + n];
            float dv = rsqrtf(d);
            dvl[n] = dv;
            ys[n] = xg[n] * dv;
            oh[n] = 0.f;
        }
        __syncthreads();
        const int* src = edge_index + (size_t)g * 2 * N_EDGES + s * EPB;
        const int2* s2 = (const int2*)src;
        const int2* d2 = (const int2*)(src + N_EDGES);
        for (int e = tid; e < EPB / 2; e += 512) {
            int2 sv = s2[e], dd = d2[e];
            atomicAdd(&oh[dd.x], ys[sv.x] * dvl[dd.x]);
            atomicAdd(&oh[dd.y], ys[sv.y] * dvl[dd.y]);
        }
        __syncthreads();
        float* op = outs_part + ((size_t)g * MSPLIT + s) * N_NODES;
        for (int n = tid; n < N_NODES; n += 512) op[n] = oh[n];
        return;
    }
    if (b < MSG_BLKS + PACK_BLKS) {
        int base = (b - MSG_BLKS) * 2048;           // 4 float4 per thread
        for (int u = 0; u < 4; u++) {
            int idx = base + u * 512 + tid;         // over BATCH*512/4
            float4 v = ((const float4*)in)[idx];
            int bb = idx >> 7;
            int c = (idx & 127) << 2;
            int r = bb / 10, slot = bb - r * 10;
            bf16x4 o = { (bf16_t)v.x, (bf16_t)v.y, (bf16_t)v.z, (bf16_t)v.w };
            *(bf16x4*)(A + (size_t)r * PACDIM_ + slot * 640 + c) = o;
        }
        return;
    }
    // transpose-convert: W [Rr][Cc] fp32 -> Wt [Cc][Rr] bf16, 64x64 tiles
    float (*t)[67] = (float(*)[67])sm;              // 64*67*4 = 17.2 KB
    const float* W; bf16_t* Wt; int Rr, Cc, r0, c0;
    if (b < MSG_BLKS + PACK_BLKS + W0T_BLKS) {
        int tile = b - (MSG_BLKS + PACK_BLKS);      // 100 x 16 tiles
        W = W0; Wt = W0t; Rr = PACDIM_; Cc = D0_;
        r0 = (tile >> 4) << 6; c0 = (tile & 15) << 6;
    } else {
        int tile = b - (MSG_BLKS + PACK_BLKS + W0T_BLKS);  // 16 x 8 tiles
        W = W1; Wt = W1t; Rr = D0_; Cc = D1_;
        r0 = (tile >> 3) << 6; c0 = (tile & 7) << 6;
    }
    for (int u = 0; u < 2; u++) {
        int idx = u * 512 + tid;                    // 1024 float4 loads
        int r = idx >> 4, c4 = (idx & 15) << 2;
        float4 v = *(const float4*)(W + (size_t)(r0 + r) * Cc + c0 + c4);
        t[r][c4] = v.x; t[r][c4 + 1] = v.y; t[r][c4 + 2] = v.z; t[r][c4 + 3] = v.w;
    }
    __syncthreads();
    {
        int c = tid >> 3, seg = tid & 7;            // 512 bf16x8 stores
        bf16x8 o;
        for (int jj = 0; jj < 8; jj++) o[jj] = (bf16_t)t[seg * 8 + jj][c];
        *(bf16x8*)(Wt + (size_t)(c0 + c) * Rr + r0 + seg * 8) = o;
    }
}

// ---------- kernel 3: finish gcn + gnoise partial GEMV (plain writes) ----------
__global__ __launch_bounds__(512) void gnoise_kernel(
    const float* __restrict__ graphs_x, const float* __restrict__ degs_part,
    const float* __restrict__ outs_part,
    const float* __restrict__ gcn_w, const float* __restrict__ gcn_b,
    const float* __restrict__ gme_w, float* __restrict__ gnoise_p)
{
    __shared__ float of[500];
    __shared__ float part[4][128];
    const int s = blockIdx.x, g = blockIdx.y, tid = threadIdx.x;
    const int nBase = s * 500;
    const float w = gcn_w[0], bb = gcn_b[0];
    const float* dgp = degs_part + (size_t)g * ESPLIT * N_NODES;
    const float* otp = outs_part + (size_t)g * MSPLIT * N_NODES;
    for (int n = tid; n < 500; n += 512) {
        int gn = nBase + n;
        float d = 1.0f, o = 0.f;
        for (int p = 0; p < ESPLIT; p++) d += dgp[(size_t)p * N_NODES + gn];
        for (int p = 0; p < MSPLIT; p++) o += otp[(size_t)p * N_NODES + gn];
        of[n] = w * (o + graphs_x[(size_t)g * N_NODES + gn] / d) + bb;
    }
    __syncthreads();
    const int j = tid & 127, ch = tid >> 7;
    float acc = 0.f;
    const int n0 = ch * 125;
    for (int n = n0; n < n0 + 125; n++)
        acc += of[n] * gme_w[(size_t)(nBase + n) * 128 + j];
    part[ch][j] = acc;
    __syncthreads();
    if (tid < 128)
        gnoise_p[((size_t)g * 4 + s) * 128 + tid] =
            part[0][tid] + part[1][tid] + part[2][tid] + part[3][tid];
}

// ------- kernel 4: meta MLP + noise cols -> A (sums 4 gnoise partials inline) -------
__global__ __launch_bounds__(256) void meta_kernel(
    const float* __restrict__ chain, const float* __restrict__ metadata,
    const int* __restrict__ graph_ids,
    const float* __restrict__ meta_w, const float* __restrict__ meta_b,
    const float* __restrict__ gme_w, const float* __restrict__ gme_b,
    const float* __restrict__ gnoise_p, bf16_t* __restrict__ A)
{
    int wid = (blockIdx.x * 256 + threadIdx.x) >> 6;
    int lane = threadIdx.x & 63;
    if (wid >= BATCH) return;
    const int b = wid;
    float me = 0.f;
    if (lane < 32) {
        me = meta_b[lane] + chain[b] * meta_w[lane];
        for (int i = 1; i < 16; i++)
            me += metadata[(size_t)b * 15 + (i - 1)] * meta_w[(size_t)i * 32 + lane];
        me = me > 0.f ? me : 0.f;
    }
    const int gid = graph_ids[b];
    const float* gp = gnoise_p + (size_t)gid * 4 * 128;
    const int j1 = lane, j2 = lane + 64;
    float n1 = gme_b[j1] + gp[j1] + gp[128 + j1] + gp[256 + j1] + gp[384 + j1];
    float n2 = gme_b[j2] + gp[j2] + gp[128 + j2] + gp[256 + j2] + gp[384 + j2];
    for (int k = 0; k < 32; k++) {
        float mk = __shfl(me, k, 64);
        const float* wrow = gme_w + (size_t)(N_NODES + k) * 128;
        n1 += mk * wrow[j1];
        n2 += mk * wrow[j2];
    }
    int r = b / 10, slot = b - r * 10;
    bf16_t* dp = A + (size_t)r * PACDIM_ + slot * 640 + TED_;
    dp[j1] = (bf16_t)n1;
    dp[j2] = (bf16_t)n2;
}

// -------- kernel 5: split-K GEMM (layer 0), double-buffered, XOR-swizzled LDS --------
__global__ __launch_bounds__(256) void gemm_bt_splitk_kernel(
    const bf16_t* __restrict__ A,   // [M,K] row-major
    const bf16_t* __restrict__ Bt,  // [N,K] row-major
    float* __restrict__ P,          // [S, Mp, N] fp32 partials
    int M, int N, int K, int KS, int zbits, int xbits, int Mp)
{
    __shared__ __align__(16) bf16_t As[2][128 * 32];
    __shared__ __align__(16) bf16_t Bs[2][128 * 32];
    const int tid = threadIdx.x;
    const int wave = tid >> 6;
    const int lane = tid & 63;
    const int id = blockIdx.x;
    const int z = id & ((1 << zbits) - 1);
    const int xt = (id >> zbits) & ((1 << xbits) - 1);
    const int yt = id >> (zbits + xbits);
    const int mBase = yt * 128;
    const int nBase = xt * 128;
    const int wm = (wave & 1) * 64;
    const int wn = (wave >> 1) * 64;

    floatx4 acc[4][4] = {};

    const int rA0 = tid >> 2;
    const int g4 = tid & 3;
    const int f4 = (rA0 >> 1) & 3;
    const int k8 = (g4 ^ f4) * 8;
    int gm0 = mBase + rA0;      if (gm0 > M - 1) gm0 = M - 1;
    int gm1 = mBase + 64 + rA0; if (gm1 > M - 1) gm1 = M - 1;
    const bf16_t* aP0 = A + (size_t)gm0 * K + k8;
    const bf16_t* aP1 = A + (size_t)gm1 * K + k8;
    const bf16_t* bP0 = Bt + (size_t)(nBase + rA0) * K + k8;
    const bf16_t* bP1 = Bt + (size_t)(nBase + 64 + rA0) * K + k8;

    const int q4 = lane >> 4;
    const int mr = lane & 15;
    const int kq = ((q4 ^ ((mr >> 1) & 3)) * 8);
    int aOff[4], bOff[4];
    for (int i = 0; i < 4; i++) aOff[i] = (wm + i * 16 + mr) * 32 + kq;
    for (int j = 0; j < 4; j++) bOff[j] = (wn + j * 16 + mr) * 32 + kq;

    const int nIter = KS >> 5;
    const int kc = z * KS;
    {   // prologue: stage tile 0 into buffer 0
        char* lA = (char*)(&As[0][0]) + wave * 1024;
        char* lB = (char*)(&Bs[0][0]) + wave * 1024;
        glds16(aP0 + kc, lA);
        glds16(aP1 + kc, lA + 4096);
        glds16(bP0 + kc, lB);
        glds16(bP1 + kc, lB + 4096);
    }
    __syncthreads();
    for (int t = 0; t < nIter; ++t) {
        const int cur = t & 1;
        if (t + 1 < nIter) {
            const int kn = kc + (t + 1) * 32;
            char* lA = (char*)(&As[cur ^ 1][0]) + wave * 1024;
            char* lB = (char*)(&Bs[cur ^ 1][0]) + wave * 1024;
            glds16(aP0 + kn, lA);
            glds16(aP1 + kn, lA + 4096);
            glds16(bP0 + kn, lB);
            glds16(bP1 + kn, lB + 4096);
        }
        const bf16_t* aB = &As[cur][0];
        const bf16_t* bB = &Bs[cur][0];
        bf16x8 af[4], bfr[4];
        for (int i = 0; i < 4; i++) af[i] = *(const bf16x8*)(aB + aOff[i]);
        for (int j = 0; j < 4; j++) bfr[j] = *(const bf16x8*)(bB + bOff[j]);
        for (int i = 0; i < 4; i++)
            for (int j = 0; j < 4; j++)
                acc[i][j] = __builtin_amdgcn_mfma_f32_16x16x32_bf16(
                    af[i], bfr[j], acc[i][j], 0, 0, 0);
        __syncthreads();
    }

    float* Pz = P + (size_t)z * Mp * N;
    const int rq = (lane >> 4) * 4;
    const int cn = lane & 15;
    for (int j = 0; j < 4; j++) {
        int col = nBase + wn + j * 16 + cn;
        for (int i = 0; i < 4; i++)
            for (int r = 0; r < 4; r++) {
                int rowm = mBase + wm + i * 16 + rq + r;
                Pz[(size_t)rowm * N + col] = acc[i][j][r];
            }
    }
}

// -------- kernel 6: reduce split-K partials + bias + leaky -> bf16; seed out=b2 --------
__global__ __launch_bounds__(256) void reduce_bias_leaky_kernel(
    const float* __restrict__ P, const float* __restrict__ bias,
    bf16_t* __restrict__ C, int M, int N, int Mp, int S,
    const float* __restrict__ b2, float* __restrict__ outp)
{
    if (blockIdx.x == 0 && threadIdx.x < MROWS / 4) {
        float bb2 = b2[0];
        ((float4*)outp)[threadIdx.x] = make_float4(bb2, bb2, bb2, bb2);
    }
    int idx = blockIdx.x * 256 + threadIdx.x;
    int total = M * (N >> 2);
    if (idx >= total) return;
    int nv = N >> 2;
    int r = idx / nv, c4 = (idx - r * nv) << 2;
    size_t off = (size_t)r * N + c4;
    size_t stride = (size_t)Mp * N;
    float4 v = *(const float4*)(P + off);
    for (int s = 1; s < S; s++) {
        float4 u = *(const float4*)(P + s * stride + off);
        v.x += u.x; v.y += u.y; v.z += u.z; v.w += u.w;
    }
    const float4 bv = *(const float4*)(bias + c4);
    v.x += bv.x; v.y += bv.y; v.z += bv.z; v.w += bv.w;
    v.x = v.x > 0.f ? v.x : 0.2f * v.x;
    v.y = v.y > 0.f ? v.y : 0.2f * v.y;
    v.z = v.z > 0.f ? v.z : 0.2f * v.z;
    v.w = v.w > 0.f ? v.w : 0.2f * v.w;
    bf16x4 o = { (bf16_t)v.x, (bf16_t)v.y, (bf16_t)v.z, (bf16_t)v.w };
    *(bf16x4*)(C + off) = o;
}

// ---- kernel 7: gemm1 (non-split, K=1024) + fused bias/leaky/dot(w2) -> atomicAdd out ----
// BM=BN=128, grid 32 blocks (x=4, y=8)
__global__ __launch_bounds__(256) void gemm1_final_kernel(
    const bf16_t* __restrict__ A,   // H1 [MROWS,1024] row-major (bf16)
    const bf16_t* __restrict__ Bt,  // W1t [512,1024] row-major (bf16)
    const float* __restrict__ b1, const float* __restrict__ w2,
    float* __restrict__ outp)
{
    __shared__ __align__(16) bf16_t As[2][128 * 32];
    __shared__ __align__(16) bf16_t Bs[2][128 * 32];
    const int K = D0_;
    const int tid = threadIdx.x;
    const int wave = tid >> 6;
    const int lane = tid & 63;
    const int xt = blockIdx.x & 3;
    const int yt = blockIdx.x >> 2;
    const int mBase = yt * 128;
    const int nBase = xt * 128;
    const int wm = (wave & 1) * 64;
    const int wn = (wave >> 1) * 64;

    floatx4 acc[4][4] = {};

    const int rA0 = tid >> 2;
    const int g4 = tid & 3;
    const int f4 = (rA0 >> 1) & 3;
    const int k8 = (g4 ^ f4) * 8;
    int gm0 = mBase + rA0;      if (gm0 > MROWS - 1) gm0 = MROWS - 1;
    int gm1 = mBase + 64 + rA0; if (gm1 > MROWS - 1) gm1 = MROWS - 1;
    const bf16_t* aP0 = A + (size_t)gm0 * K + k8;
    const bf16_t* aP1 = A + (size_t)gm1 * K + k8;
    const bf16_t* bP0 = Bt + (size_t)(nBase + rA0) * K + k8;
    const bf16_t* bP1 = Bt + (size_t)(nBase + 64 + rA0) * K + k8;

    const int q4 = lane >> 4;
    const int mr = lane & 15;
    const int kq = ((q4 ^ ((mr >> 1) & 3)) * 8);
    int aOff[4], bOff[4];
    for (int i = 0; i < 4; i++) aOff[i] = (wm + i * 16 + mr) * 32 + kq;
    for (int j = 0; j < 4; j++) bOff[j] = (wn + j * 16 + mr) * 32 + kq;

    const int nIter = K >> 5;   // 32
    {
        char* lA = (char*)(&As[0][0]) + wave * 1024;
        char* lB = (char*)(&Bs[0][0]) + wave * 1024;
        glds16(aP0, lA);
        glds16(aP1, lA + 4096);
        glds16(bP0, lB);
        glds16(bP1, lB + 4096);
    }
    __syncthreads();
    for (int t = 0; t < nIter; ++t) {
        const int cur = t & 1;
        if (t + 1 < nIter) {
            const int kn = (t + 1) * 32;
            char* lA = (char*)(&As[cur ^ 1][0]) + wave * 1024;
            char* lB = (char*)(&Bs[cur ^ 1][0]) + wave * 1024;
            glds16(aP0 + kn, lA);
            glds16(aP1 + kn, lA + 4096);
            glds16(bP0 + kn, lB);
            glds16(bP1 + kn, lB + 4096);
        }
        const bf16_t* aB = &As[cur][0];
        const bf16_t* bB = &Bs[cur][0];
        bf16x8 af[4], bfr[4];
        for (int i = 0; i < 4; i++) af[i] = *(const bf16x8*)(aB + aOff[i]);
        for (int j = 0; j < 4; j++) bfr[j] = *(const bf16x8*)(bB + bOff[j]);
        for (int i = 0; i < 4; i++)
            for (int j = 0; j < 4; j++)
                acc[i][j] = __builtin_amdgcn_mfma_f32_16x16x32_bf16(
                    af[i], bfr[j], acc[i][j], 0, 0, 0);
        __syncthreads();
    }

    // epilogue: out[row] += sum_j leaky(acc + b1[col]) * w2[col]
    const int cn = lane & 15;
    float b1v[4], w2v[4];
    for (int j = 0; j < 4; j++) {
        int col = nBase + wn + j * 16 + cn;
        b1v[j] = b1[col];
        w2v[j] = w2[col];
    }
    for (int i = 0; i < 4; i++) {
        for (int r = 0; r < 4; r++) {
            float part = 0.f;
            for (int j = 0; j < 4; j++) {
                float v = acc[i][j][r] + b1v[j];
                v = v > 0.f ? v : 0.2f * v;
                part += v * w2v[j];
            }
            for (int off = 8; off; off >>= 1) part += __shfl_xor(part, off, 16);
            if (cn == 0) {
                int rowm = mBase + wm + i * 16 + q4 * 4 + r;
                if (rowm < MROWS) atomicAdd(&outp[rowm], part);
            }
        }
    }
}

// ---------------------------- launcher ----------------------------
extern "C" void kernel_launch(void* const* d_in, const int* in_sizes, int n_in,
                              void* d_out, int out_size, void* d_ws, size_t ws_size,
                              hipStream_t stream)
{
    const float* input_    = (const float*)d_in[0];
    const float* graphs_x  = (const float*)d_in[1];
    const int*   edge_idx  = (const int*)  d_in[2];
    const int*   graph_ids = (const int*)  d_in[3];
    const float* chain     = (const float*)d_in[4];
    const float* metadata  = (const float*)d_in[5];
    const float* gcn_w     = (const float*)d_in[6];
    const float* gcn_b     = (const float*)d_in[7];
    const float* meta_w    = (const float*)d_in[8];
    const float* meta_b    = (const float*)d_in[9];
    const float* gme_w     = (const float*)d_in[10];
    const float* gme_b     = (const float*)d_in[11];
    const float* seq_w0    = (const float*)d_in[12];
    const float* seq_b0    = (const float*)d_in[13];
    const float* seq_w1    = (const float*)d_in[14];
    const float* seq_b1    = (const float*)d_in[15];
    const float* seq_w2    = (const float*)d_in[16];
    const float* seq_b2    = (const float*)d_in[17];
    float* out = (float*)d_out;

    char* ws = (char*)d_ws;
    // workspace layout (no pre-zeroing needed anywhere: all plain writes)
    float*  degs_part = (float*)(ws + 0);            // 64*8*2000*4  =  4,096,000
    float*  outs_part = (float*)(ws + 4096000);      // 64*8*2000*4  =  4,096,000
    float*  gnoise_p  = (float*)(ws + 8192000);      // 64*4*128*4   =    131,072
    bf16_t* Abuf      = (bf16_t*)(ws + 8323072);     // 1000*6400*2  = 12,800,000
    bf16_t* W0t       = (bf16_t*)(ws + 21123072);    // 6400*1024*2  = 13,107,200
    bf16_t* W1t       = (bf16_t*)(ws + 34230272);    // 1024*512*2   =  1,048,576
    bf16_t* H1        = (bf16_t*)(ws + 35278848);    // 1000*1024*2  =  2,048,000
    float*  P         = (float*)(ws + 37326848);     // 8*1024*1024*4 = 33,554,432
    // total ~70.9 MB

    // 1: degree histogram partials
    deg_kernel<<<512, 512, 0, stream>>>(edge_idx, degs_part);
    // 2: msg partials | pack input | transpose W0 | transpose W1
    //    (streaming blocks hide under latency-bound msg blocks)
    work_kernel<<<MSG_BLKS + PACK_BLKS + W0T_BLKS + W1T_BLKS, 512, 0, stream>>>(
        graphs_x, edge_idx, degs_part, outs_part,
        input_, Abuf, seq_w0, W0t, seq_w1, W1t);
    // 3: finish GCN + gnoise partial GEMV
    gnoise_kernel<<<dim3(4, G_GRAPHS), 512, 0, stream>>>(
        graphs_x, degs_part, outs_part, gcn_w, gcn_b, gme_w, gnoise_p);
    // 4: meta MLP + noise columns into A
    meta_kernel<<<2500, 256, 0, stream>>>(
        chain, metadata, graph_ids, meta_w, meta_b, gme_w, gme_b,
        gnoise_p, Abuf);

    // 5: layer 0 GEMM: M=1000 N=1024 K=6400, split-K=8, 8x8x8=512 blocks flat
    gemm_bt_splitk_kernel<<<512, 256, 0, stream>>>(
        Abuf, W0t, P, MROWS, D0_, PACDIM_, PACDIM_ / S0, 3, 3, 1024);
    // 6: reduce P -> H1 (bias+leaky, bf16); also seeds out[r] = b2
    reduce_bias_leaky_kernel<<<(MROWS * D0_ / 4 + 255) / 256, 256, 0, stream>>>(
        P, seq_b0, H1, MROWS, D0_, 1024, S0, seq_b2, out);

    // 7: layer 1 fused with final: M=1000 N=512 K=1024, 4x8=32 blocks
    gemm1_final_kernel<<<32, 256, 0, stream>>>(
        H1, W1t, seq_b1, seq_w2, out);
}

// Round 8
// 255.499 us; speedup vs baseline: 2.1049x; 1.0006x over previous
//
#include <hip/hip_runtime.h>

typedef __bf16 bf16_t;
typedef __bf16 bf16x4 __attribute__((ext_vector_type(4)));
typedef __bf16 bf16x8 __attribute__((ext_vector_type(8)));
typedef float floatx4 __attribute__((ext_vector_type(4)));

#define G_GRAPHS 64
#define N_NODES 2000
#define N_EDGES 64000
#define BATCH 10000
#define TED_ 512
#define NOISE_ 128
#define PACDIM_ 6400
#define D0_ 1024
#define D1_ 512
#define MROWS 1000   // BATCH / PAC
#define ESPLIT 8
#define EPB (N_EDGES / ESPLIT)      // 8000 edges per split block
#define MSPLIT 8
#define S0 8          // split-K for layer 0

// dispatch 1 block ranges: deg | pack
#define DEG_BLKS 512
#define PACK_BLKS 625    // 2048 float4 per block (4 per thread, 512 thr)
// dispatch 2 block ranges: msg | W0 transpose | W1 transpose
#define MSG_BLKS 512
#define W0T_BLKS 1600    // (6400/64)*(1024/64)
#define W1T_BLKS 128     // (1024/64)*(512/64)

// ---------------- async global->LDS helper (16B per lane) ----------------
__device__ __forceinline__ void glds16(const void* g, void* l) {
    __builtin_amdgcn_global_load_lds(
        (__attribute__((address_space(1))) void*)(g),
        (__attribute__((address_space(3))) void*)(l), 16, 0, 0);
}

// ========== kernel 1: deg partials | pack input (co-scheduled) ==========
// blocks [0,512): degree histogram partials (latency-bound, LDS atomics)
// blocks [512,1137): pack input_ -> A bf16 (streaming, hides under deg)
__global__ __launch_bounds__(512) void deg_pack_kernel(
    const int* __restrict__ edge_index, float* __restrict__ degs_part,
    const float* __restrict__ in, bf16_t* __restrict__ A)
{
    __shared__ float h[N_NODES];
    const int b = blockIdx.x, tid = threadIdx.x;
    if (b < DEG_BLKS) {
        const int s = b & 7, g = b >> 3;
        for (int n = tid; n < N_NODES; n += 512) h[n] = 0.f;
        __syncthreads();
        const int4* d4 = (const int4*)(edge_index + (size_t)g * 2 * N_EDGES
                                       + N_EDGES + s * EPB);
        for (int e = tid; e < EPB / 4; e += 512) {
            int4 v = d4[e];
            atomicAdd(&h[v.x], 1.0f); atomicAdd(&h[v.y], 1.0f);
            atomicAdd(&h[v.z], 1.0f); atomicAdd(&h[v.w], 1.0f);
        }
        __syncthreads();
        float* dp = degs_part + ((size_t)g * ESPLIT + s) * N_NODES;
        for (int n = tid; n < N_NODES; n += 512) dp[n] = h[n];
        return;
    }
    {
        int base = (b - DEG_BLKS) * 2048;           // 4 float4 per thread
        for (int u = 0; u < 4; u++) {
            int idx = base + u * 512 + tid;         // over BATCH*512/4
            float4 v = ((const float4*)in)[idx];
            int bb = idx >> 7;
            int c = (idx & 127) << 2;
            int r = bb / 10, slot = bb - r * 10;
            bf16x4 o = { (bf16_t)v.x, (bf16_t)v.y, (bf16_t)v.z, (bf16_t)v.w };
            *(bf16x4*)(A + (size_t)r * PACDIM_ + slot * 640 + c) = o;
        }
    }
}

// ========== kernel 2: work (msg | transpose W0/W1) ==========
// blocks [0,512): message-pass partials (latency-bound, LDS atomics)
// blocks [512,2112): transpose W0 -> W0t bf16 (vectorized, hides under msg)
// blocks [2112,2240): transpose W1 -> W1t bf16
__global__ __launch_bounds__(512) void work_kernel(
    const float* __restrict__ graphs_x, const int* __restrict__ edge_index,
    const float* __restrict__ degs_part, float* __restrict__ outs_part,
    const float* __restrict__ W0, bf16_t* __restrict__ W0t,
    const float* __restrict__ W1, bf16_t* __restrict__ W1t)
{
    __shared__ __align__(16) float sm[3 * N_NODES];   // 24 KB; aliased by transpose
    const int b = blockIdx.x, tid = threadIdx.x;

    if (b < MSG_BLKS) {
        float* ys  = sm;                 // x[n]*dinv[n]
        float* dvl = sm + N_NODES;       // dinv[n]
        float* oh  = sm + 2 * N_NODES;
        const int s = b & 7, g = b >> 3;
        const float* xg = graphs_x + (size_t)g * N_NODES;
        const float* dgp = degs_part + (size_t)g * ESPLIT * N_NODES;
        for (int n = tid; n < N_NODES; n += 512) {
            float d = 1.0f;                            // +1 self-loop
            for (int p = 0; p < ESPLIT; p++) d += dgp[(size_t)p * N_NODES + n];
            float dv = rsqrtf(d);
            dvl[n] = dv;
            ys[n] = xg[n] * dv;
            oh[n] = 0.f;
        }
        __syncthreads();
        const int* src = edge_index + (size_t)g * 2 * N_EDGES + s * EPB;
        const int2* s2 = (const int2*)src;
        const int2* d2 = (const int2*)(src + N_EDGES);
        for (int e = tid; e < EPB / 2; e += 512) {
            int2 sv = s2[e], dd = d2[e];
            atomicAdd(&oh[dd.x], ys[sv.x] * dvl[dd.x]);
            atomicAdd(&oh[dd.y], ys[sv.y] * dvl[dd.y]);
        }
        __syncthreads();
        float* op = outs_part + ((size_t)g * MSPLIT + s) * N_NODES;
        for (int n = tid; n < N_NODES; n += 512) op[n] = oh[n];
        return;
    }
    // transpose-convert: W [Rr][Cc] fp32 -> Wt [Cc][Rr] bf16, 64x64 tiles
    float (*t)[67] = (float(*)[67])sm;              // 64*67*4 = 17.2 KB
    const float* W; bf16_t* Wt; int Rr, Cc, r0, c0;
    if (b < MSG_BLKS + W0T_BLKS) {
        int tile = b - MSG_BLKS;                    // 100 x 16 tiles
        W = W0; Wt = W0t; Rr = PACDIM_; Cc = D0_;
        r0 = (tile >> 4) << 6; c0 = (tile & 15) << 6;
    } else {
        int tile = b - (MSG_BLKS + W0T_BLKS);       // 16 x 8 tiles
        W = W1; Wt = W1t; Rr = D0_; Cc = D1_;
        r0 = (tile >> 3) << 6; c0 = (tile & 7) << 6;
    }
    for (int u = 0; u < 2; u++) {
        int idx = u * 512 + tid;                    // 1024 float4 loads
        int r = idx >> 4, c4 = (idx & 15) << 2;
        float4 v = *(const float4*)(W + (size_t)(r0 + r) * Cc + c0 + c4);
        t[r][c4] = v.x; t[r][c4 + 1] = v.y; t[r][c4 + 2] = v.z; t[r][c4 + 3] = v.w;
    }
    __syncthreads();
    {
        int c = tid >> 3, seg = tid & 7;            // 512 bf16x8 stores
        bf16x8 o;
        for (int jj = 0; jj < 8; jj++) o[jj] = (bf16_t)t[seg * 8 + jj][c];
        *(bf16x8*)(Wt + (size_t)(c0 + c) * Rr + r0 + seg * 8) = o;
    }
}

// ---------- kernel 3: finish gcn + gnoise partial GEMV (plain writes) ----------
__global__ __launch_bounds__(512) void gnoise_kernel(
    const float* __restrict__ graphs_x, const float* __restrict__ degs_part,
    const float* __restrict__ outs_part,
    const float* __restrict__ gcn_w, const float* __restrict__ gcn_b,
    const float* __restrict__ gme_w, float* __restrict__ gnoise_p)
{
    __shared__ float of[500];
    __shared__ float part[4][128];
    const int s = blockIdx.x, g = blockIdx.y, tid = threadIdx.x;
    const int nBase = s * 500;
    const float w = gcn_w[0], bb = gcn_b[0];
    const float* dgp = degs_part + (size_t)g * ESPLIT * N_NODES;
    const float* otp = outs_part + (size_t)g * MSPLIT * N_NODES;
    for (int n = tid; n < 500; n += 512) {
        int gn = nBase + n;
        float d = 1.0f, o = 0.f;
        for (int p = 0; p < ESPLIT; p++) d += dgp[(size_t)p * N_NODES + gn];
        for (int p = 0; p < MSPLIT; p++) o += otp[(size_t)p * N_NODES + gn];
        of[n] = w * (o + graphs_x[(size_t)g * N_NODES + gn] / d) + bb;
    }
    __syncthreads();
    const int j = tid & 127, ch = tid >> 7;
    float acc = 0.f;
    const int n0 = ch * 125;
    for (int n = n0; n < n0 + 125; n++)
        acc += of[n] * gme_w[(size_t)(nBase + n) * 128 + j];
    part[ch][j] = acc;
    __syncthreads();
    if (tid < 128)
        gnoise_p[((size_t)g * 4 + s) * 128 + tid] =
            part[0][tid] + part[1][tid] + part[2][tid] + part[3][tid];
}

// ------- kernel 4: meta MLP + noise cols -> A (sums 4 gnoise partials inline) -------
__global__ __launch_bounds__(256) void meta_kernel(
    const float* __restrict__ chain, const float* __restrict__ metadata,
    const int* __restrict__ graph_ids,
    const float* __restrict__ meta_w, const float* __restrict__ meta_b,
    const float* __restrict__ gme_w, const float* __restrict__ gme_b,
    const float* __restrict__ gnoise_p, bf16_t* __restrict__ A)
{
    int wid = (blockIdx.x * 256 + threadIdx.x) >> 6;
    int lane = threadIdx.x & 63;
    if (wid >= BATCH) return;
    const int b = wid;
    float me = 0.f;
    if (lane < 32) {
        me = meta_b[lane] + chain[b] * meta_w[lane];
        for (int i = 1; i < 16; i++)
            me += metadata[(size_t)b * 15 + (i - 1)] * meta_w[(size_t)i * 32 + lane];
        me = me > 0.f ? me : 0.f;
    }
    const int gid = graph_ids[b];
    const float* gp = gnoise_p + (size_t)gid * 4 * 128;
    const int j1 = lane, j2 = lane + 64;
    float n1 = gme_b[j1] + gp[j1] + gp[128 + j1] + gp[256 + j1] + gp[384 + j1];
    float n2 = gme_b[j2] + gp[j2] + gp[128 + j2] + gp[256 + j2] + gp[384 + j2];
    for (int k = 0; k < 32; k++) {
        float mk = __shfl(me, k, 64);
        const float* wrow = gme_w + (size_t)(N_NODES + k) * 128;
        n1 += mk * wrow[j1];
        n2 += mk * wrow[j2];
    }
    int r = b / 10, slot = b - r * 10;
    bf16_t* dp = A + (size_t)r * PACDIM_ + slot * 640 + TED_;
    dp[j1] = (bf16_t)n1;
    dp[j2] = (bf16_t)n2;
}

// -------- kernel 5: split-K GEMM (layer 0), double-buffered, XOR-swizzled LDS --------
__global__ __launch_bounds__(256) void gemm_bt_splitk_kernel(
    const bf16_t* __restrict__ A,   // [M,K] row-major
    const bf16_t* __restrict__ Bt,  // [N,K] row-major
    float* __restrict__ P,          // [S, Mp, N] fp32 partials
    int M, int N, int K, int KS, int zbits, int xbits, int Mp)
{
    __shared__ __align__(16) bf16_t As[2][128 * 32];
    __shared__ __align__(16) bf16_t Bs[2][128 * 32];
    const int tid = threadIdx.x;
    const int wave = tid >> 6;
    const int lane = tid & 63;
    const int id = blockIdx.x;
    const int z = id & ((1 << zbits) - 1);
    const int xt = (id >> zbits) & ((1 << xbits) - 1);
    const int yt = id >> (zbits + xbits);
    const int mBase = yt * 128;
    const int nBase = xt * 128;
    const int wm = (wave & 1) * 64;
    const int wn = (wave >> 1) * 64;

    floatx4 acc[4][4] = {};

    const int rA0 = tid >> 2;
    const int g4 = tid & 3;
    const int f4 = (rA0 >> 1) & 3;
    const int k8 = (g4 ^ f4) * 8;
    int gm0 = mBase + rA0;      if (gm0 > M - 1) gm0 = M - 1;
    int gm1 = mBase + 64 + rA0; if (gm1 > M - 1) gm1 = M - 1;
    const bf16_t* aP0 = A + (size_t)gm0 * K + k8;
    const bf16_t* aP1 = A + (size_t)gm1 * K + k8;
    const bf16_t* bP0 = Bt + (size_t)(nBase + rA0) * K + k8;
    const bf16_t* bP1 = Bt + (size_t)(nBase + 64 + rA0) * K + k8;

    const int q4 = lane >> 4;
    const int mr = lane & 15;
    const int kq = ((q4 ^ ((mr >> 1) & 3)) * 8);
    int aOff[4], bOff[4];
    for (int i = 0; i < 4; i++) aOff[i] = (wm + i * 16 + mr) * 32 + kq;
    for (int j = 0; j < 4; j++) bOff[j] = (wn + j * 16 + mr) * 32 + kq;

    const int nIter = KS >> 5;
    const int kc = z * KS;
    {   // prologue: stage tile 0 into buffer 0
        char* lA = (char*)(&As[0][0]) + wave * 1024;
        char* lB = (char*)(&Bs[0][0]) + wave * 1024;
        glds16(aP0 + kc, lA);
        glds16(aP1 + kc, lA + 4096);
        glds16(bP0 + kc, lB);
        glds16(bP1 + kc, lB + 4096);
    }
    __syncthreads();
    for (int t = 0; t < nIter; ++t) {
        const int cur = t & 1;
        if (t + 1 < nIter) {
            const int kn = kc + (t + 1) * 32;
            char* lA = (char*)(&As[cur ^ 1][0]) + wave * 1024;
            char* lB = (char*)(&Bs[cur ^ 1][0]) + wave * 1024;
            glds16(aP0 + kn, lA);
            glds16(aP1 + kn, lA + 4096);
            glds16(bP0 + kn, lB);
            glds16(bP1 + kn, lB + 4096);
        }
        const bf16_t* aB = &As[cur][0];
        const bf16_t* bB = &Bs[cur][0];
        bf16x8 af[4], bfr[4];
        for (int i = 0; i < 4; i++) af[i] = *(const bf16x8*)(aB + aOff[i]);
        for (int j = 0; j < 4; j++) bfr[j] = *(const bf16x8*)(bB + bOff[j]);
        for (int i = 0; i < 4; i++)
            for (int j = 0; j < 4; j++)
                acc[i][j] = __builtin_amdgcn_mfma_f32_16x16x32_bf16(
                    af[i], bfr[j], acc[i][j], 0, 0, 0);
        __syncthreads();
    }

    float* Pz = P + (size_t)z * Mp * N;
    const int rq = (lane >> 4) * 4;
    const int cn = lane & 15;
    for (int j = 0; j < 4; j++) {
        int col = nBase + wn + j * 16 + cn;
        for (int i = 0; i < 4; i++)
            for (int r = 0; r < 4; r++) {
                int rowm = mBase + wm + i * 16 + rq + r;
                Pz[(size_t)rowm * N + col] = acc[i][j][r];
            }
    }
}

// -------- kernel 6: reduce split-K partials + bias + leaky -> bf16; seed out=b2 --------
__global__ __launch_bounds__(256) void reduce_bias_leaky_kernel(
    const float* __restrict__ P, const float* __restrict__ bias,
    bf16_t* __restrict__ C, int M, int N, int Mp, int S,
    const float* __restrict__ b2, float* __restrict__ outp)
{
    if (blockIdx.x == 0 && threadIdx.x < MROWS / 4) {
        float bb2 = b2[0];
        ((float4*)outp)[threadIdx.x] = make_float4(bb2, bb2, bb2, bb2);
    }
    int idx = blockIdx.x * 256 + threadIdx.x;
    int total = M * (N >> 2);
    if (idx >= total) return;
    int nv = N >> 2;
    int r = idx / nv, c4 = (idx - r * nv) << 2;
    size_t off = (size_t)r * N + c4;
    size_t stride = (size_t)Mp * N;
    float4 v = *(const float4*)(P + off);
    for (int s = 1; s < S; s++) {
        float4 u = *(const float4*)(P + s * stride + off);
        v.x += u.x; v.y += u.y; v.z += u.z; v.w += u.w;
    }
    const float4 bv = *(const float4*)(bias + c4);
    v.x += bv.x; v.y += bv.y; v.z += bv.z; v.w += bv.w;
    v.x = v.x > 0.f ? v.x : 0.2f * v.x;
    v.y = v.y > 0.f ? v.y : 0.2f * v.y;
    v.z = v.z > 0.f ? v.z : 0.2f * v.z;
    v.w = v.w > 0.f ? v.w : 0.2f * v.w;
    bf16x4 o = { (bf16_t)v.x, (bf16_t)v.y, (bf16_t)v.z, (bf16_t)v.w };
    *(bf16x4*)(C + off) = o;
}

// ---- kernel 7: gemm1 (non-split, K=1024) + fused bias/leaky/dot(w2) -> atomicAdd out ----
// BM=BN=128, grid 32 blocks (x=4, y=8)
__global__ __launch_bounds__(256) void gemm1_final_kernel(
    const bf16_t* __restrict__ A,   // H1 [MROWS,1024] row-major (bf16)
    const bf16_t* __restrict__ Bt,  // W1t [512,1024] row-major (bf16)
    const float* __restrict__ b1, const float* __restrict__ w2,
    float* __restrict__ outp)
{
    __shared__ __align__(16) bf16_t As[2][128 * 32];
    __shared__ __align__(16) bf16_t Bs[2][128 * 32];
    const int K = D0_;
    const int tid = threadIdx.x;
    const int wave = tid >> 6;
    const int lane = tid & 63;
    const int xt = blockIdx.x & 3;
    const int yt = blockIdx.x >> 2;
    const int mBase = yt * 128;
    const int nBase = xt * 128;
    const int wm = (wave & 1) * 64;
    const int wn = (wave >> 1) * 64;

    floatx4 acc[4][4] = {};

    const int rA0 = tid >> 2;
    const int g4 = tid & 3;
    const int f4 = (rA0 >> 1) & 3;
    const int k8 = (g4 ^ f4) * 8;
    int gm0 = mBase + rA0;      if (gm0 > MROWS - 1) gm0 = MROWS - 1;
    int gm1 = mBase + 64 + rA0; if (gm1 > MROWS - 1) gm1 = MROWS - 1;
    const bf16_t* aP0 = A + (size_t)gm0 * K + k8;
    const bf16_t* aP1 = A + (size_t)gm1 * K + k8;
    const bf16_t* bP0 = Bt + (size_t)(nBase + rA0) * K + k8;
    const bf16_t* bP1 = Bt + (size_t)(nBase + 64 + rA0) * K + k8;

    const int q4 = lane >> 4;
    const int mr = lane & 15;
    const int kq = ((q4 ^ ((mr >> 1) & 3)) * 8);
    int aOff[4], bOff[4];
    for (int i = 0; i < 4; i++) aOff[i] = (wm + i * 16 + mr) * 32 + kq;
    for (int j = 0; j < 4; j++) bOff[j] = (wn + j * 16 + mr) * 32 + kq;

    const int nIter = K >> 5;   // 32
    {
        char* lA = (char*)(&As[0][0]) + wave * 1024;
        char* lB = (char*)(&Bs[0][0]) + wave * 1024;
        glds16(aP0, lA);
        glds16(aP1, lA + 4096);
        glds16(bP0, lB);
        glds16(bP1, lB + 4096);
    }
    __syncthreads();
    for (int t = 0; t < nIter; ++t) {
        const int cur = t & 1;
        if (t + 1 < nIter) {
            const int kn = (t + 1) * 32;
            char* lA = (char*)(&As[cur ^ 1][0]) + wave * 1024;
            char* lB = (char*)(&Bs[cur ^ 1][0]) + wave * 1024;
            glds16(aP0 + kn, lA);
            glds16(aP1 + kn, lA + 4096);
            glds16(bP0 + kn, lB);
            glds16(bP1 + kn, lB + 4096);
        }
        const bf16_t* aB = &As[cur][0];
        const bf16_t* bB = &Bs[cur][0];
        bf16x8 af[4], bfr[4];
        for (int i = 0; i < 4; i++) af[i] = *(const bf16x8*)(aB + aOff[i]);
        for (int j = 0; j < 4; j++) bfr[j] = *(const bf16x8*)(bB + bOff[j]);
        for (int i = 0; i < 4; i++)
            for (int j = 0; j < 4; j++)
                acc[i][j] = __builtin_amdgcn_mfma_f32_16x16x32_bf16(
                    af[i], bfr[j], acc[i][j], 0, 0, 0);
        __syncthreads();
    }

    // epilogue: out[row] += sum_j leaky(acc + b1[col]) * w2[col]
    const int cn = lane & 15;
    float b1v[4], w2v[4];
    for (int j = 0; j < 4; j++) {
        int col = nBase + wn + j * 16 + cn;
        b1v[j] = b1[col];
        w2v[j] = w2[col];
    }
    for (int i = 0; i < 4; i++) {
        for (int r = 0; r < 4; r++) {
            float part = 0.f;
            for (int j = 0; j < 4; j++) {
                float v = acc[i][j][r] + b1v[j];
                v = v > 0.f ? v : 0.2f * v;
                part += v * w2v[j];
            }
            for (int off = 8; off; off >>= 1) part += __shfl_xor(part, off, 16);
            if (cn == 0) {
                int rowm = mBase + wm + i * 16 + q4 * 4 + r;
                if (rowm < MROWS) atomicAdd(&outp[rowm], part);
            }
        }
    }
}

// ---------------------------- launcher ----------------------------
extern "C" void kernel_launch(void* const* d_in, const int* in_sizes, int n_in,
                              void* d_out, int out_size, void* d_ws, size_t ws_size,
                              hipStream_t stream)
{
    const float* input_    = (const float*)d_in[0];
    const float* graphs_x  = (const float*)d_in[1];
    const int*   edge_idx  = (const int*)  d_in[2];
    const int*   graph_ids = (const int*)  d_in[3];
    const float* chain     = (const float*)d_in[4];
    const float* metadata  = (const float*)d_in[5];
    const float* gcn_w     = (const float*)d_in[6];
    const float* gcn_b     = (const float*)d_in[7];
    const float* meta_w    = (const float*)d_in[8];
    const float* meta_b    = (const float*)d_in[9];
    const float* gme_w     = (const float*)d_in[10];
    const float* gme_b     = (const float*)d_in[11];
    const float* seq_w0    = (const float*)d_in[12];
    const float* seq_b0    = (const float*)d_in[13];
    const float* seq_w1    = (const float*)d_in[14];
    const float* seq_b1    = (const float*)d_in[15];
    const float* seq_w2    = (const float*)d_in[16];
    const float* seq_b2    = (const float*)d_in[17];
    float* out = (float*)d_out;

    char* ws = (char*)d_ws;
    // workspace layout (no pre-zeroing needed anywhere: all plain writes)
    float*  degs_part = (float*)(ws + 0);            // 64*8*2000*4  =  4,096,000
    float*  outs_part = (float*)(ws + 4096000);      // 64*8*2000*4  =  4,096,000
    float*  gnoise_p  = (float*)(ws + 8192000);      // 64*4*128*4   =    131,072
    bf16_t* Abuf      = (bf16_t*)(ws + 8323072);     // 1000*6400*2  = 12,800,000
    bf16_t* W0t       = (bf16_t*)(ws + 21123072);    // 6400*1024*2  = 13,107,200
    bf16_t* W1t       = (bf16_t*)(ws + 34230272);    // 1024*512*2   =  1,048,576
    bf16_t* H1        = (bf16_t*)(ws + 35278848);    // 1000*1024*2  =  2,048,000
    float*  P         = (float*)(ws + 37326848);     // 8*1024*1024*4 = 33,554,432
    // total ~70.9 MB

    // 1: degree histogram partials | pack input (streaming hides under deg)
    deg_pack_kernel<<<DEG_BLKS + PACK_BLKS, 512, 0, stream>>>(
        edge_idx, degs_part, input_, Abuf);
    // 2: msg partials | transpose W0 | transpose W1 (streaming hides under msg)
    work_kernel<<<MSG_BLKS + W0T_BLKS + W1T_BLKS, 512, 0, stream>>>(
        graphs_x, edge_idx, degs_part, outs_part,
        seq_w0, W0t, seq_w1, W1t);
    // 3: finish GCN + gnoise partial GEMV
    gnoise_kernel<<<dim3(4, G_GRAPHS), 512, 0, stream>>>(
        graphs_x, degs_part, outs_part, gcn_w, gcn_b, gme_w, gnoise_p);
    // 4: meta MLP + noise columns into A
    meta_kernel<<<2500, 256, 0, stream>>>(
        chain, metadata, graph_ids, meta_w, meta_b, gme_w, gme_b,
        gnoise_p, Abuf);

    // 5: layer 0 GEMM: M=1000 N=1024 K=6400, split-K=8, 8x8x8=512 blocks flat
    gemm_bt_splitk_kernel<<<512, 256, 0, stream>>>(
        Abuf, W0t, P, MROWS, D0_, PACDIM_, PACDIM_ / S0, 3, 3, 1024);
    // 6: reduce P -> H1 (bias+leaky, bf16); also seeds out[r] = b2
    reduce_bias_leaky_kernel<<<(MROWS * D0_ / 4 + 255) / 256, 256, 0, stream>>>(
        P, seq_b0, H1, MROWS, D0_, 1024, S0, seq_b2, out);

    // 7: layer 1 fused with final: M=1000 N=512 K=1024, 4x8=32 blocks
    gemm1_final_kernel<<<32, 256, 0, stream>>>(
        H1, W1t, seq_b1, seq_w2, out);
}